// Round 15
// baseline (90.695 us; speedup 1.0000x reference)
//
#include <hip/hip_runtime.h>
#include <hip/hip_fp16.h>

#define GRIDN 256
#define NVOX (GRIDN * GRIDN * GRIDN)   // 64 MiB fp32
#define NYT  32                        // y-tiles of 8 rows
#define NBKT (GRIDN * NYT)             // 8192 base buckets: key = z*32 + (y>>3)
#define NSUB 8                         // sub-buckets by (bid & 7) (~1 XCD each)
#define SBCAP 32                       // per-(key,sub) capacity (lambda 7.6)

#define TYF   8
#define WROWS 12                       // y0-2 .. y0+9
#define ZS    4                        // z-seg: 2048 blocks -> 8 blocks/CU of work
#define NITER (ZS + 4)                 // 8 slice iterations per block
#define NTHR  256

typedef float floatx4 __attribute__((ext_vector_type(4)));

// LDS-only barrier: don't drain vmcnt (record prefetch + NT output stores
// stay in flight across it).
#define BAR_LDS()                                              \
    do {                                                       \
        asm volatile("s_waitcnt lgkmcnt(0)" ::: "memory");     \
        __builtin_amdgcn_sched_barrier(0);                     \
        __builtin_amdgcn_s_barrier();                          \
        __builtin_amdgcn_sched_barrier(0);                     \
    } while (0)

// ---------------------------------------------------------------------------
// Bin: sub-bucket (key, s=bid&7); cnt [s][key] so each 64B line is same-XCD.
// record = {x:8, y:8, f16:16}.
// ---------------------------------------------------------------------------
__global__ __launch_bounds__(NTHR) void k_bin(const float* __restrict__ feats,
                                              const int* __restrict__ coords,
                                              int* __restrict__ cnt,
                                              unsigned int* __restrict__ rec, int n) {
    int i = blockIdx.x * NTHR + threadIdx.x;
    if (i >= n) return;
    int d = coords[3 * i + 0];
    int h = coords[3 * i + 1];
    int w = coords[3 * i + 2];
    int s   = blockIdx.x & (NSUB - 1);
    int key = s * NBKT + d * NYT + (h >> 3);
    int slot = atomicAdd(&cnt[key], 1);
    if (slot < SBCAP) {
        unsigned int r = (unsigned int)w | ((unsigned int)h << 8)
                       | ((unsigned int)__half_as_ushort(__float2half(feats[i])) << 16);
        rec[((size_t)key << 5) + slot] = r;
    }
}

// ---------------------------------------------------------------------------
// Sparse fused 5x5x5 box conv, v6: SMALL z-seg for block-level parallelism.
// Tile 256(x) x 8(y) x 4(z out); grid 2048 (8 blocks/CU of work); LDS ~26KB
// -> 6 resident blocks/CU (24 waves, 75%): stalls in one block hide behind
// 5 others + refill. (R2's one-shot 4096-block xypass at ~5 TB/s vs every
// 1024-block looping variant pinned at 1.5 TB/s = the evidence.)
// Schedule per slice k (R11-proven 2-barrier, 2-buffer):
//   B_top; prefetch k+1 records; scatter k -> Xp[cb]; B_mid;
//   y-pass k from Xp[cb]; zero Xp[cb^1]; z-ring; NT store (k>=4).
// ---------------------------------------------------------------------------
__global__ __launch_bounds__(NTHR) void k_fused_sparse(const int* __restrict__ cnt,
                                                       const unsigned int* __restrict__ rec,
                                                       float* __restrict__ out) {
    __shared__ float Xp[2][WROWS][256];      // 24 KB
    __shared__ int   cms[NITER][24];         // counts per (slice k, seg q=t*8+s)
    __shared__ int   rbs[NITER][24];         // rec base per (k, q)

    const int tid = threadIdx.x;
    int wg  = blockIdx.x;
    int swz = (wg & 7) * 256 + (wg >> 3);    // XCD-chunked, bijective (2048%8==0)
    const int y0 = (swz & 31) * TYF;
    const int z0 = (swz >> 5) * ZS;

    const int xq  = (tid & 63) * 4;          // float4 col in the row
    const int yy2 = (tid >> 6) * 2;          // 2 output rows per thread
    const int yt0 = y0 >> 3;

    // Prologue: load NITERx24 sub-bucket counts/bases; zero both buffers.
    for (int idx = tid; idx < NITER * 24; idx += NTHR) {
        int k = idx / 24, q = idx - 24 * k;
        int t = q >> 3, s = q & 7;
        int zi = z0 - 2 + k;
        int yt = yt0 - 1 + t;
        int m = 0, b = 0;
        if ((unsigned)zi < (unsigned)GRIDN && (unsigned)yt < (unsigned)NYT) {
            int key = s * NBKT + zi * NYT + yt;
            m = min(cnt[key], SBCAP);
            b = key << 5;
        }
        cms[k][q] = m;
        rbs[k][q] = b;
    }
    for (int idx = tid; idx < 2 * WROWS * 64; idx += NTHR)
        ((float4*)Xp)[idx] = make_float4(0.f, 0.f, 0.f, 0.f);
    BAR_LDS();

    // Static slots: reg r, thread tid -> L = r*256+tid, seg q = L>>5, slot L&31.
    const int q0s = (0 * 256 + tid) >> 5, sl = tid & 31;
    const int q1s = (1 * 256 + tid) >> 5;
    const int q2s = (2 * 256 + tid) >> 5;

    auto fetch = [&](int k, unsigned int& r0, unsigned int& r1, unsigned int& r2) {
        r0 = (sl < cms[k][q0s]) ? rec[rbs[k][q0s] + sl] : 0u;
        r1 = (sl < cms[k][q1s]) ? rec[rbs[k][q1s] + sl] : 0u;
        r2 = (sl < cms[k][q2s]) ? rec[rbs[k][q2s] + sl] : 0u;
    };

    unsigned int p0, p1, p2;
    fetch(0, p0, p1, p2);

    float4 a0 = {0,0,0,0}, a1 = {0,0,0,0}, a2 = {0,0,0,0}, a3 = {0,0,0,0}, a4 = {0,0,0,0};
    float4 b0 = {0,0,0,0}, b1 = {0,0,0,0}, b2 = {0,0,0,0}, b3 = {0,0,0,0}, b4 = {0,0,0,0};

    for (int k = 0; k < NITER; ++k) {
        const int cbuf = k & 1;
        BAR_LDS();                           // B_top: Xp[cbuf] zeroed; prior reads done
        // Prefetch slice k+1 (in flight across both barriers).
        unsigned int n0 = 0, n1 = 0, n2 = 0;
        if (k + 1 < NITER) fetch(k + 1, n0, n1, n2);
        // Scatter slice k into Xp[cbuf].
        {
            float (*buf)[256] = Xp[cbuf];
            auto scat = [&](unsigned int r, int ok) {
                if (!ok) return;
                int x  = r & 255;
                int y  = (r >> 8) & 255;
                int ry = y - y0 + 2;
                if ((unsigned)ry < (unsigned)WROWS) {
                    float f = __half2float(__ushort_as_half((unsigned short)(r >> 16)));
                    #pragma unroll
                    for (int dx = -2; dx <= 2; ++dx) {
                        int cc = x + dx;
                        if ((unsigned)cc < 256u)
                            atomicAdd(&buf[ry][cc], f);
                    }
                }
            };
            scat(p0, sl < cms[k][q0s]);
            scat(p1, sl < cms[k][q1s]);
            scat(p2, sl < cms[k][q2s]);
        }
        BAR_LDS();                           // B_mid: scatter complete
        // y-pass slice k: 6 rows -> 2 output rows (shared middle sum).
        {
            float (*pb)[256] = Xp[cbuf];
            float4 r0 = *(const float4*)&pb[yy2 + 0][xq];
            float4 r1 = *(const float4*)&pb[yy2 + 1][xq];
            float4 r2 = *(const float4*)&pb[yy2 + 2][xq];
            float4 r3 = *(const float4*)&pb[yy2 + 3][xq];
            float4 r4 = *(const float4*)&pb[yy2 + 4][xq];
            float4 r5 = *(const float4*)&pb[yy2 + 5][xq];
            float4 sm, v0, v1;
            sm.x = r1.x + r2.x + r3.x + r4.x;  sm.y = r1.y + r2.y + r3.y + r4.y;
            sm.z = r1.z + r2.z + r3.z + r4.z;  sm.w = r1.w + r2.w + r3.w + r4.w;
            v0.x = sm.x + r0.x; v0.y = sm.y + r0.y; v0.z = sm.z + r0.z; v0.w = sm.w + r0.w;
            v1.x = sm.x + r5.x; v1.y = sm.y + r5.y; v1.z = sm.z + r5.z; v1.w = sm.w + r5.w;
            a0 = a1; a1 = a2; a2 = a3; a3 = a4; a4 = v0;
            b0 = b1; b1 = b2; b2 = b3; b3 = b4; b4 = v1;
        }
        // Zero the OTHER buffer for slice k+1 (its reads ended before B_top(k)).
        if (k + 1 < NITER) {
            float4* zb = (float4*)Xp[cbuf ^ 1];
            for (int idx = tid; idx < WROWS * 64; idx += NTHR)
                zb[idx] = make_float4(0.f, 0.f, 0.f, 0.f);
        }
        // Store output slice zo = z0+k-4 (z-ring full from k>=4).
        if (k >= 4) {
            int zo = z0 + k - 4;
            floatx4 s0, s1;
            s0.x = a0.x + a1.x + a2.x + a3.x + a4.x;
            s0.y = a0.y + a1.y + a2.y + a3.y + a4.y;
            s0.z = a0.z + a1.z + a2.z + a3.z + a4.z;
            s0.w = a0.w + a1.w + a2.w + a3.w + a4.w;
            s1.x = b0.x + b1.x + b2.x + b3.x + b4.x;
            s1.y = b0.y + b1.y + b2.y + b3.y + b4.y;
            s1.z = b0.z + b1.z + b2.z + b3.z + b4.z;
            s1.w = b0.w + b1.w + b2.w + b3.w + b4.w;
            float* base = out + (size_t)zo * (GRIDN * GRIDN);
            __builtin_nontemporal_store(s0, (floatx4*)(base + (size_t)(y0 + yy2) * GRIDN + xq));
            __builtin_nontemporal_store(s1, (floatx4*)(base + (size_t)(y0 + yy2 + 1) * GRIDN + xq));
        }
        p0 = n0; p1 = n1; p2 = n2;
    }
}

// ---------------------------------------------------------------------------
// Fallback if ws too small: zero out, then 125-way atomic expansion.
// ---------------------------------------------------------------------------
__global__ __launch_bounds__(256) void k_zero4(floatx4* __restrict__ p, int n4) {
    int stride = gridDim.x * blockDim.x;
    floatx4 z = {0.f, 0.f, 0.f, 0.f};
    for (int i = blockIdx.x * blockDim.x + threadIdx.x; i < n4; i += stride)
        __builtin_nontemporal_store(z, &p[i]);
}

__global__ void k_scatter125(const float* __restrict__ feats,
                             const int* __restrict__ coords,
                             float* __restrict__ out, int n) {
    int i = blockIdx.x * blockDim.x + threadIdx.x;
    if (i >= n) return;
    int d = coords[3 * i + 0];
    int h = coords[3 * i + 1];
    int w = coords[3 * i + 2];
    float f = feats[i];
    int d0 = max(d - 2, 0), d1 = min(d + 2, GRIDN - 1);
    int h0 = max(h - 2, 0), h1 = min(h + 2, GRIDN - 1);
    int w0 = max(w - 2, 0), w1 = min(w + 2, GRIDN - 1);
    for (int dd = d0; dd <= d1; ++dd)
        for (int hh = h0; hh <= h1; ++hh)
            for (int ww = w0; ww <= w1; ++ww)
                atomicAdd(&out[(dd * GRIDN + hh) * GRIDN + ww], f);
}

extern "C" void kernel_launch(void* const* d_in, const int* in_sizes, int n_in,
                              void* d_out, int out_size, void* d_ws, size_t ws_size,
                              hipStream_t stream) {
    const float* feats  = (const float*)d_in[0];
    const int*   coords = (const int*)d_in[1];
    float*       out    = (float*)d_out;
    int n = in_sizes[0];

    const size_t cnt_bytes = (size_t)NSUB * NBKT * sizeof(int);                  // 256 KiB
    const size_t rec_bytes = (size_t)NSUB * NBKT * SBCAP * sizeof(unsigned int); // 8 MiB

    if (ws_size >= cnt_bytes + rec_bytes) {
        int*          cnt = (int*)d_ws;
        unsigned int* rec = (unsigned int*)((char*)d_ws + cnt_bytes);
        hipMemsetAsync(cnt, 0, cnt_bytes, stream);
        k_bin<<<(n + NTHR - 1) / NTHR, NTHR, 0, stream>>>(feats, coords, cnt, rec, n);
        k_fused_sparse<<<(GRIDN / TYF) * (GRIDN / ZS), NTHR, 0, stream>>>(cnt, rec, out);
    } else {
        k_zero4<<<4096, 256, 0, stream>>>((floatx4*)out, NVOX / 4);
        k_scatter125<<<(n + 255) / 256, 256, 0, stream>>>(feats, coords, out, n);
    }
}

// Round 16
// 77.883 us; speedup vs baseline: 1.1645x; 1.1645x over previous
//
#include <hip/hip_runtime.h>
#include <hip/hip_fp16.h>

#define GRIDN 256
#define NVOX (GRIDN * GRIDN * GRIDN)   // 64 MiB fp32
#define NYT  32                        // y-tiles of 8 rows
#define NBKT (GRIDN * NYT)             // 8192 base buckets: key = z*32 + (y>>3)
#define NSUB 8                         // sub-buckets by (bid & 7)  (~1 XCD each)
#define SBCAP 32                       // per-(key,sub) capacity (lambda 7.6)

#define TYF   8
#define WROWS 12                       // y0-2 .. y0+9
#define ZS    8
#define NTHR  256

typedef float floatx4 __attribute__((ext_vector_type(4)));

// LDS-only barrier: don't drain vmcnt (record prefetch stays in flight).
#define BAR_LDS()                                              \
    do {                                                       \
        asm volatile("s_waitcnt lgkmcnt(0)" ::: "memory");     \
        __builtin_amdgcn_sched_barrier(0);                     \
        __builtin_amdgcn_s_barrier();                          \
        __builtin_amdgcn_sched_barrier(0);                     \
    } while (0)

// ---------------------------------------------------------------------------
// Bin: sub-bucket (key, s=bid&7); cnt [s][key] so each 64B line is same-XCD.
// record = {x:8, y:8, f16:16}.
// ---------------------------------------------------------------------------
__global__ __launch_bounds__(NTHR) void k_bin(const float* __restrict__ feats,
                                              const int* __restrict__ coords,
                                              int* __restrict__ cnt,
                                              unsigned int* __restrict__ rec, int n) {
    int i = blockIdx.x * NTHR + threadIdx.x;
    if (i >= n) return;
    int d = coords[3 * i + 0];
    int h = coords[3 * i + 1];
    int w = coords[3 * i + 2];
    int s   = blockIdx.x & (NSUB - 1);
    int key = s * NBKT + d * NYT + (h >> 3);
    int slot = atomicAdd(&cnt[key], 1);
    if (slot < SBCAP) {
        unsigned int r = (unsigned int)w | ((unsigned int)h << 8)
                       | ((unsigned int)__half_as_ushort(__float2half(feats[i])) << 16);
        rec[((size_t)key << 5) + slot] = r;
    }
}

// ---------------------------------------------------------------------------
// Sparse fused 5x5x5 box conv — R14 structure, NORMAL output stores.
// (R9's nontemporal stores bypassed L2 write-combining: every NT variant
// derived to ~65us while R8's normal-store variant was <=44. Single-variable
// revert this round.)
// 3-buffer rotation, ONE barrier per slice, statically-slotted records.
// Block = 256 thr, tile 256(x) x 8(y) x 8(z out). Grid 1024, XCD-swizzled.
// ---------------------------------------------------------------------------
__global__ __launch_bounds__(NTHR) void k_fused_sparse(const int* __restrict__ cnt,
                                                       const unsigned int* __restrict__ rec,
                                                       float* __restrict__ out) {
    __shared__ float Xp[3][WROWS][256];
    __shared__ int   cms[ZS + 4][24];    // count per (slice k, seg q=(t*8+s))
    __shared__ int   rbs[ZS + 4][24];    // rec base index per (k, q)

    const int tid = threadIdx.x;
    int wg  = blockIdx.x;
    int swz = (wg & 7) * 128 + (wg >> 3);        // XCD-chunked, bijective (1024%8==0)
    const int y0 = (swz & 31) * TYF;
    const int z0 = (swz >> 5) * ZS;

    const int xq  = (tid & 63) * 4;    // float4 col in the row
    const int yy2 = (tid >> 6) * 2;    // 2 output rows per thread
    const int yt0 = y0 >> 3;

    // Prologue: load 12x24 sub-bucket counts/bases; zero all 3 buffers.
    for (int idx = tid; idx < (ZS + 4) * 24; idx += NTHR) {
        int k = idx / 24, q = idx - 24 * k;
        int t = q >> 3, s = q & 7;
        int zi = z0 - 2 + k;
        int yt = yt0 - 1 + t;
        int m = 0, b = 0;
        if ((unsigned)zi < (unsigned)GRIDN && (unsigned)yt < (unsigned)NYT) {
            int key = s * NBKT + zi * NYT + yt;
            m = min(cnt[key], SBCAP);
            b = key << 5;
        }
        cms[k][q] = m;
        rbs[k][q] = b;
    }
    for (int idx = tid; idx < 3 * WROWS * 64; idx += NTHR)
        ((float4*)Xp)[idx] = make_float4(0.f, 0.f, 0.f, 0.f);
    BAR_LDS();

    // Static slots: reg r, thread tid -> L = r*256+tid, seg q = L>>5, slot = L&31.
    const int q0s = (0 * 256 + tid) >> 5, sl0 = tid & 31;
    const int q1s = (1 * 256 + tid) >> 5, sl1 = tid & 31;
    const int q2s = (2 * 256 + tid) >> 5, sl2 = tid & 31;

    auto fetch = [&](int k, unsigned int& r0, unsigned int& r1, unsigned int& r2) {
        r0 = (sl0 < cms[k][q0s]) ? rec[rbs[k][q0s] + sl0] : 0u;
        r1 = (sl1 < cms[k][q1s]) ? rec[rbs[k][q1s] + sl1] : 0u;
        r2 = (sl2 < cms[k][q2s]) ? rec[rbs[k][q2s] + sl2] : 0u;
    };

    unsigned int p0, p1, p2;
    fetch(0, p0, p1, p2);

    float4 a0 = {0,0,0,0}, a1 = {0,0,0,0}, a2 = {0,0,0,0}, a3 = {0,0,0,0}, a4 = {0,0,0,0};
    float4 b0 = {0,0,0,0}, b1 = {0,0,0,0}, b2 = {0,0,0,0}, b3 = {0,0,0,0}, b4 = {0,0,0,0};

    for (int k = 0; k <= ZS + 4; ++k) {
        // Prefetch slice k+1 (in flight across the barrier).
        unsigned int n0 = 0, n1 = 0, n2 = 0;
        if (k + 1 <= ZS + 3) fetch(k + 1, n0, n1, n2);

        // Scatter slice k into buf k%3.
        if (k <= ZS + 3) {
            float (*buf)[256] = Xp[k % 3];
            auto scat = [&](unsigned int r, int ok) {
                if (!ok) return;
                int x  = r & 255;
                int y  = (r >> 8) & 255;
                int ry = y - y0 + 2;
                if ((unsigned)ry < (unsigned)WROWS) {
                    float f = __half2float(__ushort_as_half((unsigned short)(r >> 16)));
                    #pragma unroll
                    for (int dx = -2; dx <= 2; ++dx) {
                        int cc = x + dx;
                        if ((unsigned)cc < 256u)
                            atomicAdd(&buf[ry][cc], f);
                    }
                }
            };
            scat(p0, sl0 < cms[k][q0s]);
            scat(p1, sl1 < cms[k][q1s]);
            scat(p2, sl2 < cms[k][q2s]);
        }
        // Zero buf (k+1)%3 (y-passed at iter k-1; one barrier since).
        if (k + 1 <= ZS + 3) {
            float4* zb = (float4*)Xp[(k + 1) % 3];
            for (int idx = tid; idx < WROWS * 64; idx += NTHR)
                zb[idx] = make_float4(0.f, 0.f, 0.f, 0.f);
        }
        // y-pass slice k-1 from buf (k-1)%3 (scattered at k-1; barrier since).
        if (k >= 1) {
            float (*pb)[256] = Xp[(k - 1) % 3];
            float4 r0 = *(const float4*)&pb[yy2 + 0][xq];
            float4 r1 = *(const float4*)&pb[yy2 + 1][xq];
            float4 r2 = *(const float4*)&pb[yy2 + 2][xq];
            float4 r3 = *(const float4*)&pb[yy2 + 3][xq];
            float4 r4 = *(const float4*)&pb[yy2 + 4][xq];
            float4 r5 = *(const float4*)&pb[yy2 + 5][xq];
            float4 sm, v0, v1;
            sm.x = r1.x + r2.x + r3.x + r4.x;  sm.y = r1.y + r2.y + r3.y + r4.y;
            sm.z = r1.z + r2.z + r3.z + r4.z;  sm.w = r1.w + r2.w + r3.w + r4.w;
            v0.x = sm.x + r0.x; v0.y = sm.y + r0.y; v0.z = sm.z + r0.z; v0.w = sm.w + r0.w;
            v1.x = sm.x + r5.x; v1.y = sm.y + r5.y; v1.z = sm.z + r5.z; v1.w = sm.w + r5.w;
            a0 = a1; a1 = a2; a2 = a3; a3 = a4; a4 = v0;
            b0 = b1; b1 = b2; b2 = b3; b3 = b4; b4 = v1;
            int j = k - 1;
            if (j >= 4) {
                int zo = z0 + j - 4;
                float4 s0, s1;
                s0.x = a0.x + a1.x + a2.x + a3.x + a4.x;
                s0.y = a0.y + a1.y + a2.y + a3.y + a4.y;
                s0.z = a0.z + a1.z + a2.z + a3.z + a4.z;
                s0.w = a0.w + a1.w + a2.w + a3.w + a4.w;
                s1.x = b0.x + b1.x + b2.x + b3.x + b4.x;
                s1.y = b0.y + b1.y + b2.y + b3.y + b4.y;
                s1.z = b0.z + b1.z + b2.z + b3.z + b4.z;
                s1.w = b0.w + b1.w + b2.w + b3.w + b4.w;
                float* base = out + (size_t)zo * (GRIDN * GRIDN);
                // NORMAL cached stores (the single change this round).
                *(float4*)(base + (size_t)(y0 + yy2) * GRIDN + xq)     = s0;
                *(float4*)(base + (size_t)(y0 + yy2 + 1) * GRIDN + xq) = s1;
            }
        }
        BAR_LDS();
        p0 = n0; p1 = n1; p2 = n2;
    }
}

// ---------------------------------------------------------------------------
// Fallback if ws too small: zero out, then 125-way atomic expansion.
// ---------------------------------------------------------------------------
__global__ __launch_bounds__(256) void k_zero4(float4* __restrict__ p, int n4) {
    int stride = gridDim.x * blockDim.x;
    float4 z = make_float4(0.f, 0.f, 0.f, 0.f);
    for (int i = blockIdx.x * blockDim.x + threadIdx.x; i < n4; i += stride)
        p[i] = z;
}

__global__ void k_scatter125(const float* __restrict__ feats,
                             const int* __restrict__ coords,
                             float* __restrict__ out, int n) {
    int i = blockIdx.x * blockDim.x + threadIdx.x;
    if (i >= n) return;
    int d = coords[3 * i + 0];
    int h = coords[3 * i + 1];
    int w = coords[3 * i + 2];
    float f = feats[i];
    int d0 = max(d - 2, 0), d1 = min(d + 2, GRIDN - 1);
    int h0 = max(h - 2, 0), h1 = min(h + 2, GRIDN - 1);
    int w0 = max(w - 2, 0), w1 = min(w + 2, GRIDN - 1);
    for (int dd = d0; dd <= d1; ++dd)
        for (int hh = h0; hh <= h1; ++hh)
            for (int ww = w0; ww <= w1; ++ww)
                atomicAdd(&out[(dd * GRIDN + hh) * GRIDN + ww], f);
}

extern "C" void kernel_launch(void* const* d_in, const int* in_sizes, int n_in,
                              void* d_out, int out_size, void* d_ws, size_t ws_size,
                              hipStream_t stream) {
    const float* feats  = (const float*)d_in[0];
    const int*   coords = (const int*)d_in[1];
    float*       out    = (float*)d_out;
    int n = in_sizes[0];

    const size_t cnt_bytes = (size_t)NSUB * NBKT * sizeof(int);                  // 256 KiB
    const size_t rec_bytes = (size_t)NSUB * NBKT * SBCAP * sizeof(unsigned int); // 8 MiB

    if (ws_size >= cnt_bytes + rec_bytes) {
        int*          cnt = (int*)d_ws;
        unsigned int* rec = (unsigned int*)((char*)d_ws + cnt_bytes);
        hipMemsetAsync(cnt, 0, cnt_bytes, stream);
        k_bin<<<(n + NTHR - 1) / NTHR, NTHR, 0, stream>>>(feats, coords, cnt, rec, n);
        k_fused_sparse<<<1024, NTHR, 0, stream>>>(cnt, rec, out);
    } else {
        k_zero4<<<4096, 256, 0, stream>>>((float4*)out, NVOX / 4);
        k_scatter125<<<(n + 255) / 256, 256, 0, stream>>>(feats, coords, out, n);
    }
}